// Round 1
// 640.716 us; speedup vs baseline: 1.2341x; 1.2341x over previous
//
#include <hip/hip_runtime.h>
#include <math.h>

// K0: segment start offsets from sorted segment ids.
// segstart[b] = first n with seg[n] >= b ; segstart[B] = N. Covers empty segs.
__global__ __launch_bounds__(256) void k_segstart(
        const int* __restrict__ seg, int* __restrict__ segstart, int N, int B) {
    int i = blockIdx.x * blockDim.x + threadIdx.x;
    if (i >= N) return;
    int s = seg[i];
    int p = (i == 0) ? -1 : seg[i - 1];
    for (int bb = p + 1; bb <= s; ++bb) segstart[bb] = i;
    if (i == N - 1)
        for (int bb = s + 1; bb <= B; ++bb) segstart[bb] = N;
}

// K1: one block per segment. 256 threads = 8 row-groups x 32 column-lanes.
// SINGLE streaming pass over feat: per row compute gate g (partial dot +
// 5-step butterfly), online-update (m, s) AND the rescaled weighted
// accumulator acc = sum exp(g-m)*f. Raw g is stored to workspace so a tiny
// third kernel can emit alpha. Rows are processed 4 at a time so the four
// butterfly chains (5 dependent cross-lane ops each, LDS-pipe latency) are
// independent and overlap; next 4 rows are prefetched during the reduce.
__global__ __launch_bounds__(256) void k_pool(
        const float* __restrict__ feat, const float* __restrict__ w,
        const float* __restrict__ bptr, const int* __restrict__ segstart,
        float* __restrict__ gbuf, float* __restrict__ Mbuf,
        float* __restrict__ invbuf, float* __restrict__ readout) {
    int b = blockIdx.x;
    int start = segstart[b], end = segstart[b + 1];
    int t = threadIdx.x, rg = t >> 5, cl = t & 31;

    const float4 w4 = ((const float4*)w)[cl];
    const float bias = bptr[0];
    const float4* featv = (const float4*)feat;

    float m = -INFINITY, s = 0.0f;
    float4 acc = make_float4(0.0f, 0.0f, 0.0f, 0.0f);

    const int n0 = start + rg;

#define LDROW(dst, row)                                                       \
    dst = ((row) < end) ? featv[(size_t)(row) * 32 + cl]                      \
                        : make_float4(0.0f, 0.0f, 0.0f, 0.0f)

    float4 f0, f1, f2, f3;
    LDROW(f0, n0);
    LDROW(f1, n0 + 8);
    LDROW(f2, n0 + 16);
    LDROW(f3, n0 + 24);

#define UPDATE(v, f, row) do {                                                \
        if ((row) < end) {                                                    \
            float g = (v) + bias;                                             \
            if (cl == 0) gbuf[row] = g;                                       \
            float e;                                                          \
            if (g > m) {                                                      \
                float r = __expf(m - g);  /* exp(-inf)=0 on first row */      \
                s *= r;                                                       \
                acc.x *= r; acc.y *= r; acc.z *= r; acc.w *= r;               \
                m = g; e = 1.0f;                                              \
            } else {                                                          \
                e = __expf(g - m);                                            \
            }                                                                 \
            s += e;                                                           \
            acc.x += f.x * e; acc.y += f.y * e;                               \
            acc.z += f.z * e; acc.w += f.w * e;                               \
        } } while (0)

    for (int n = n0; n < end; n += 32) {
        float4 p0, p1, p2, p3;
        LDROW(p0, n + 32);
        LDROW(p1, n + 40);
        LDROW(p2, n + 48);
        LDROW(p3, n + 56);

        float v0 = f0.x * w4.x + f0.y * w4.y + f0.z * w4.z + f0.w * w4.w;
        float v1 = f1.x * w4.x + f1.y * w4.y + f1.z * w4.z + f1.w * w4.w;
        float v2 = f2.x * w4.x + f2.y * w4.y + f2.z * w4.z + f2.w * w4.w;
        float v3 = f3.x * w4.x + f3.y * w4.y + f3.z * w4.z + f3.w * w4.w;
        // 4 independent butterfly chains, interleaved (xor<32 stays in half-wave)
        #pragma unroll
        for (int d = 1; d < 32; d <<= 1) {
            v0 += __shfl_xor(v0, d);
            v1 += __shfl_xor(v1, d);
            v2 += __shfl_xor(v2, d);
            v3 += __shfl_xor(v3, d);
        }

        UPDATE(v0, f0, n);
        UPDATE(v1, f1, n + 8);
        UPDATE(v2, f2, n + 16);
        UPDATE(v3, f3, n + 24);

        f0 = p0; f1 = p1; f2 = p2; f3 = p3;
    }

    // ---- combine the 8 row-groups ----
    __shared__ float mred[8], sred[8];
    if (cl == 0) { mred[rg] = m; sred[rg] = s; }
    __syncthreads();
    float M = -INFINITY;
    #pragma unroll
    for (int g2 = 0; g2 < 8; ++g2) M = fmaxf(M, mred[g2]);
    float S = 0.0f;
    #pragma unroll
    for (int g2 = 0; g2 < 8; ++g2)
        if (sred[g2] > 0.0f) S += sred[g2] * __expf(mred[g2] - M);
    const float inv = (S > 0.0f) ? 1.0f / S : 0.0f;

    // rescale this group's accumulator to the global max (guard empty group:
    // m-M would be -inf-(-inf)=NaN when s==0)
    float r = (s > 0.0f) ? __expf(m - M) : 0.0f;
    acc.x *= r; acc.y *= r; acc.z *= r; acc.w *= r;

    __shared__ float4 red[256];
    red[t] = acc;
    __syncthreads();
    #pragma unroll
    for (int off = 4; off >= 1; off >>= 1) {
        if (rg < off) {
            float4 o = red[t + off * 32];
            red[t].x += o.x; red[t].y += o.y; red[t].z += o.z; red[t].w += o.w;
        }
        __syncthreads();
    }
    if (rg == 0) {
        float4 o = red[t];
        o.x *= inv; o.y *= inv; o.z *= inv; o.w *= inv;
        ((float4*)(readout + (size_t)b * 128))[cl] = o;
    }
    if (t == 0) { Mbuf[b] = M; invbuf[b] = inv; }
}

// K2: alpha[n] = exp(g[n] - M[seg[n]]) * inv[seg[n]]. ~12 MB traffic.
__global__ __launch_bounds__(256) void k_alpha(
        const float* __restrict__ gbuf, const int* __restrict__ seg,
        const float* __restrict__ Mbuf, const float* __restrict__ invbuf,
        float* __restrict__ alpha, int N) {
    int i = blockIdx.x * blockDim.x + threadIdx.x;
    int i4 = i * 4;
    if (i4 + 3 < N) {
        float4 g = ((const float4*)gbuf)[i];
        int4 sv = ((const int4*)seg)[i];
        float4 a;
        a.x = __expf(g.x - Mbuf[sv.x]) * invbuf[sv.x];
        a.y = __expf(g.y - Mbuf[sv.y]) * invbuf[sv.y];
        a.z = __expf(g.z - Mbuf[sv.z]) * invbuf[sv.z];
        a.w = __expf(g.w - Mbuf[sv.w]) * invbuf[sv.w];
        ((float4*)alpha)[i] = a;
    } else if (i4 < N) {
        for (int k = i4; k < N; ++k) {
            int sb = seg[k];
            alpha[k] = __expf(gbuf[k] - Mbuf[sb]) * invbuf[sb];
        }
    }
}

extern "C" void kernel_launch(void* const* d_in, const int* in_sizes, int n_in,
                              void* d_out, int out_size, void* d_ws, size_t ws_size,
                              hipStream_t stream) {
    const float* feat  = (const float*)d_in[0];
    const float* wgate = (const float*)d_in[1];
    const float* bgate = (const float*)d_in[2];
    const int*   seg   = (const int*)d_in[3];

    const int N = in_sizes[3];              // 1,000,000 nodes
    const int D = in_sizes[1];              // 128
    const int B = (out_size - N) / D;       // 1024 graphs

    float* readout = (float*)d_out;                    // [B,128]
    float* alpha   = (float*)d_out + (size_t)B * 128;  // [N]

    // workspace layout: segstart | Mbuf | invbuf | gbuf (all 256B-aligned)
    int* segstart = (int*)d_ws;
    size_t off = (((size_t)(B + 1) * 4) + 255) & ~(size_t)255;
    float* Mbuf = (float*)((char*)d_ws + off);
    float* invbuf = Mbuf + B;
    size_t off2 = (off + (size_t)2 * B * 4 + 255) & ~(size_t)255;
    float* gbuf = (float*)((char*)d_ws + off2);

    k_segstart<<<(N + 255) / 256, 256, 0, stream>>>(seg, segstart, N, B);
    k_pool<<<B, 256, 0, stream>>>(feat, wgate, bgate, segstart,
                                  gbuf, Mbuf, invbuf, readout);
    int threads4 = (N + 3) / 4;
    k_alpha<<<(threads4 + 255) / 256, 256, 0, stream>>>(gbuf, seg, Mbuf, invbuf,
                                                        alpha, N);
}